// Round 10
// baseline (590.992 us; speedup 1.0000x reference)
//
#include <hip/hip_runtime.h>
#include <stdint.h>

#define N_PTS 8192
#define N_B 8
#define NGROUP 512
#define GSIZE 32
#define BIGF 1e10f

#define THREADS 512
#define TOT_BLOCKS 256
#define FPS_BLOCKS 8
#define KNN_BLOCKS (TOT_BLOCKS - FPS_BLOCKS)   // 248

#define K1_PPT 16            // fps points per thread
#define K1_WAVES 8

#define K2_PPT 16
#define K2_WAVES 8

// partial record: 48B stride (12 words) -> record w words {12w,12w+1} mod 32 are
// pairwise disjoint banks; lanes sharing a record broadcast. Conflict-free.
#define PART_STRIDE 12

#define FMAX3(a, b, c) fmaxf(fmaxf((a), (b)), (c))

typedef float v2f __attribute__((ext_vector_type(2)));

// ---------------- DPP reductions ------------------------------------------------------
#define DPP_STEP_UMIN(ctrl, rmask)                                                 \
    { unsigned t = (unsigned)__builtin_amdgcn_update_dpp(                          \
            (int)v, (int)v, ctrl, rmask, 0xF, false);                              \
      v = (t < v) ? t : v; }

__device__ __forceinline__ unsigned wave_umin32(unsigned v) {
    DPP_STEP_UMIN(0x111, 0xF);
    DPP_STEP_UMIN(0x112, 0xF);
    DPP_STEP_UMIN(0x114, 0xF);
    DPP_STEP_UMIN(0x118, 0xF);
    DPP_STEP_UMIN(0x142, 0xA);
    DPP_STEP_UMIN(0x143, 0xC);
    return v;   // lane 63 valid
}

#define DPP_STEP_FMAX(ctrl, rmask)                                                 \
    v = fmaxf(v, __int_as_float(__builtin_amdgcn_update_dpp(                       \
            __float_as_int(v), __float_as_int(v), ctrl, rmask, 0xF, false)))

__device__ __forceinline__ float wave_fmax(float v) {
    DPP_STEP_FMAX(0x111, 0xF);
    DPP_STEP_FMAX(0x112, 0xF);
    DPP_STEP_FMAX(0x114, 0xF);
    DPP_STEP_FMAX(0x118, 0xF);
    DPP_STEP_FMAX(0x142, 0xA);
    DPP_STEP_FMAX(0x143, 0xC);
    return v;   // lane 63 valid
}

// 3-step f32 DPP max over 8-lane groups (records replicate every 8 lanes)
__device__ __forceinline__ float group8_fmax(float v) {
    DPP_STEP_FMAX(0x111, 0xF);
    DPP_STEP_FMAX(0x112, 0xF);
    DPP_STEP_FMAX(0x114, 0xF);
    return v;   // lane 63 valid (max of its 8-group == max of all 8 records)
}

__device__ __forceinline__ int rdlane63_i(int v) {
    return __builtin_amdgcn_readlane(v, 63);
}

__device__ __forceinline__ unsigned fxform(unsigned u) {
    return u ^ (unsigned)(((int)u >> 31) | 0x80000000);
}

// bitonic sort (ascending) of an N-element register array of u64
template<int N>
__device__ __forceinline__ void bitonic_sort(unsigned long long* a) {
#pragma unroll
    for (int k = 2; k <= N; k <<= 1) {
#pragma unroll
        for (int j = k >> 1; j > 0; j >>= 1) {
#pragma unroll
            for (int i = 0; i < N; ++i) {
                int ixj = i ^ j;
                if (ixj > i) {
                    bool up = ((i & k) == 0);
                    unsigned long long x = a[i], y = a[ixj];
                    bool sw = up ? (x > y) : (x < y);
                    if (sw) { a[i] = y; a[ixj] = x; }
                }
            }
        }
    }
}

// LDS overlay: fps needs swizzled lx/ly/lz + partial records; knn needs wtop+nlist+qshare.
union SharedLDS {
    struct {
        float lx[N_PTS]; float ly[N_PTS]; float lz[N_PTS];   // 96 KB, swizzled
        // record w at [w*12]: word 0 = dist bits, word 1 = global idx
        unsigned part[2][K1_WAVES * PART_STRIDE];            // dbuf, 768 B
    } f;
    struct {
        unsigned long long wtop[K2_WAVES][GSIZE];            // 2 KB
        unsigned nlist[GSIZE];
        int qshare;
    } k;
};

// ---------------- fused kernel --------------------------------------------------------
// Blocks 0..7: FPS (R7 structure — proven best across 9 experiment rounds: R2
// pre-barrier chain + overlapped post-barrier coord window. Alternatives measured
// slower: multi-batch (R3), coord-in-record folds (R4/R5/R6), barrier-free spin
// handshake (R8), packed min/max rewrite (R9)).
// fps_idx written once per group with a RELAXED agent atomic store — the datum is
// its own ready-flag (poison 0xAA < 0, indices >= 0).
// Blocks 8..255: kNN workers; tid0 RELAXED-atomic-spins on fps_idx[b,g] >= 0, LDS-
// broadcasts it, __syncthreads() orders the block.
extern "C" __global__ __launch_bounds__(THREADS, 1) void fused_kernel(
    const float* __restrict__ xyz, float* __restrict__ out,
    int* __restrict__ fps_idx)
{
    __shared__ SharedLDS S;
    const int bid = blockIdx.x;
    const int tid = threadIdx.x;
    const int lane = tid & 63;
    const int wid  = tid >> 6;

    if (bid < FPS_BLOCKS) {
        // =========================== FPS (batch = bid) ===============================
        const int b = bid;
        const float* base = xyz + (size_t)b * N_PTS * 6;
        const float4* b4 = (const float4*)base;

        v2f px[8], py[8], pz[8];
        float dd[K1_PPT];

        const int tb = tid * 24;
#pragma unroll
        for (int c = 0; c < 4; ++c) {
            float4 f0 = b4[tb + c * 6 + 0];
            float4 f1 = b4[tb + c * 6 + 1];
            float4 f2 = b4[tb + c * 6 + 2];
            float4 f3 = b4[tb + c * 6 + 3];
            float4 f4 = b4[tb + c * 6 + 4];
            float4 f5 = b4[tb + c * 6 + 5];
            px[c * 2 + 0] = (v2f){f0.x, f1.z};
            py[c * 2 + 0] = (v2f){f0.y, f1.w};
            pz[c * 2 + 0] = (v2f){f0.z, f2.x};
            px[c * 2 + 1] = (v2f){f3.x, f4.z};
            py[c * 2 + 1] = (v2f){f3.y, f4.w};
            pz[c * 2 + 1] = (v2f){f3.z, f5.x};
        }
        // swizzled staging: point p = tid*16+i at A(p) = (i<<9)+tid (conflict-free)
#pragma unroll
        for (int i = 0; i < K1_PPT; ++i) {
            int a = (i << 9) + tid;
            S.f.lx[a] = px[i >> 1][i & 1];
            S.f.ly[a] = py[i >> 1][i & 1];
            S.f.lz[a] = pz[i >> 1][i & 1];
            dd[i] = BIGF;
        }
        __syncthreads();

        unsigned cur = 0;
        float cx = S.f.lx[0], cy = S.f.ly[0], cz = S.f.lz[0];   // point 0: A(0)=0

        for (int it = 0; it < NGROUP; ++it) {
            if (tid == 0) {
                // single relaxed store: fire-and-forget; datum doubles as flag.
                // NOTE: intentionally never vmcnt-drained inside the loop.
                __hip_atomic_store(&fps_idx[b * NGROUP + it], (int)cur,
                                   __ATOMIC_RELAXED, __HIP_MEMORY_SCOPE_AGENT);
            }
            if (it == NGROUP - 1) break;

            // packed min-update: per pair v_pk_sub x3, v_pk_mul x3, v_pk_add x2.
            // contract(off) forbids mul+add fusion -> exact (dx^2+dy^2)+dz^2 order,
            // bitwise identical per half to the scalar reference path.
            {
#pragma clang fp contract(off)
                v2f c2x = {cx, cx};
                v2f c2y = {cy, cy};
                v2f c2z = {cz, cz};
#pragma unroll
                for (int q = 0; q < 8; ++q) {
                    v2f dx = px[q] - c2x;
                    v2f dy = py[q] - c2y;
                    v2f dz = pz[q] - c2z;
                    v2f s  = (dx * dx + dy * dy) + dz * dz;
                    dd[2 * q + 0] = fminf(dd[2 * q + 0], s[0]);
                    dd[2 * q + 1] = fminf(dd[2 * q + 1], s[1]);
                }
            }

            // post-loop argmax: v_max3 tree (8 ops) + downward equality scan
            // (keeps SMALLEST matching i -> identical tie semantics to running '>').
            float t0 = FMAX3(dd[0],  dd[1],  dd[2]);
            float t1 = FMAX3(dd[3],  dd[4],  dd[5]);
            float t2 = FMAX3(dd[6],  dd[7],  dd[8]);
            float t3 = FMAX3(dd[9],  dd[10], dd[11]);
            float t4 = FMAX3(dd[12], dd[13], dd[14]);
            float bestd = fmaxf(FMAX3(t0, t1, t2), FMAX3(t3, t4, dd[15]));
            unsigned besti = 0;
#pragma unroll
            for (int i = K1_PPT - 1; i >= 0; --i)
                besti = (dd[i] == bestd) ? (unsigned)i : besti;

            unsigned bestp = (unsigned)tid * K1_PPT + besti;

            // wave argmax: f32 DPP max, then first tied lane (= smallest global index,
            // since lane order == index order within the wave).
            float wm = __int_as_float(rdlane63_i(__float_as_int(wave_fmax(bestd))));
            unsigned long long bal = __ballot(bestd == wm);
            int L = (int)(__ffsll((long long)bal) - 1);

            // 2-word partial {dist, idx}: the WINNING lane writes its own values
            // directly (bestd == wm bitwise by ballot; its bestp IS the wave winner)
            // — deletes the readlane(bestp, L) from the serial chain.
            if (lane == L) {
                unsigned* rec = &S.f.part[it & 1][wid * PART_STRIDE];
                rec[0] = __float_as_uint(bestd);
                rec[1] = bestp;
            }

            // barrier WITHOUT the implicit vmcnt(0) drain of __syncthreads():
            // only the LDS write must be visible (lgkmcnt); the relaxed fps_idx
            // publish store stays in flight across the barrier. (R8 measured the
            // barrier-free spin alternative at +120us — s_barrier is the cheap path.)
            asm volatile("s_waitcnt lgkmcnt(0)" ::: "memory");
            __builtin_amdgcn_s_barrier();
            __builtin_amdgcn_sched_barrier(0);   // pin the ds_reads below after barrier

            // Window 1: read record (lane&7) = {dist, idx}.
            const unsigned* rr = &S.f.part[it & 1][(lane & 7) * PART_STRIDE];
            float    rv = __uint_as_float(rr[0]);
            unsigned ri = rr[1];

            // Speculative coord read for candidate (lane&7), issued IMMEDIATELY —
            // overlaps the DPP reduce below. 8 distinct addresses × 8-lane broadcast
            // groups. Unconditionally consumed by readlane -> cannot be sunk (R4 bug).
            int wa = (int)(((ri & 15u) << 9) + (ri >> 4));
            float rx = S.f.lx[wa];
            float ry = S.f.ly[wa];
            float rz = S.f.lz[wa];
            __builtin_amdgcn_sched_barrier(0);   // coord reads issue before the chain

            // Slim reduce: 3-step f32 DPP max over dist + ballot. First tied lane =
            // smallest record id = smallest wave id = smallest global index (wave
            // index ranges disjoint & ascending; each record carries its wave's
            // smallest tied index) — identical tie semantics to the u64-key path.
            float wm2 = __int_as_float(rdlane63_i(__float_as_int(group8_fmax(rv))));
            unsigned long long b2 = __ballot(rv == wm2);
            int W = (int)(__ffsll((long long)b2) - 1);   // in [0,8)
            cur = (unsigned)__builtin_amdgcn_readlane((int)ri, W);
            // Coord data arrived during the DPP chain; lane W holds winner's coords.
            cx = __int_as_float(__builtin_amdgcn_readlane(__float_as_int(rx), W));
            cy = __int_as_float(__builtin_amdgcn_readlane(__float_as_int(ry), W));
            cz = __int_as_float(__builtin_amdgcn_readlane(__float_as_int(rz), W));
        }
        return;
    }

    // ============================= kNN worker blocks =================================
    const int OFF1 = N_B * NGROUP * GSIZE * 3;   // neigh_attr
    const int OFF2 = 2 * OFF1;                   // center
    const int OFF3 = OFF2 + N_B * NGROUP * 3;    // center_attribute

    for (int idx = bid - FPS_BLOCKS; idx < N_B * NGROUP; idx += KNN_BLOCKS) {
        const int g = idx >> 3;
        const int b = idx & 7;
        const float* base = xyz + (size_t)b * N_PTS * 6;

        if (tid == 0) {
            // relaxed atomic spin on the datum itself (L2 read, caches stay warm)
            int qv;
            while ((qv = __hip_atomic_load(&fps_idx[b * NGROUP + g], __ATOMIC_RELAXED,
                                           __HIP_MEMORY_SCOPE_AGENT)) < 0)
                __builtin_amdgcn_s_sleep(32);
            S.k.qshare = qv;
        }
        __syncthreads();   // orders qshare + all S.k reuse from previous group

        const int qq = __builtin_amdgcn_readfirstlane(S.k.qshare);
        const float cx = base[qq * 6 + 0];
        const float cy = base[qq * 6 + 1];
        const float cz = base[qq * 6 + 2];
        // ||c||^2: separate square, left-assoc add, NO FMA
        const float cn = __fadd_rn(__fadd_rn(__fmul_rn(cx, cx), __fmul_rn(cy, cy)),
                                   __fmul_rn(cz, cz));

        const float4* b4 = (const float4*)base;
        const int tb = tid * 24;

        unsigned long long keys[K2_PPT];

#pragma unroll
        for (int c = 0; c < 4; ++c) {
            float4 f0 = b4[tb + c * 6 + 0];
            float4 f1 = b4[tb + c * 6 + 1];
            float4 f2 = b4[tb + c * 6 + 2];
            float4 f3 = b4[tb + c * 6 + 3];
            float4 f4 = b4[tb + c * 6 + 4];
            float4 f5 = b4[tb + c * 6 + 5];
            float X[4] = {f0.x, f1.z, f3.x, f4.z};
            float Y[4] = {f0.y, f1.w, f3.y, f4.w};
            float Z[4] = {f0.z, f2.x, f3.z, f5.x};
#pragma unroll
            for (int j = 0; j < 4; ++j) {
                float x = X[j], y = Y[j], z = Z[j];
                float xn  = __fadd_rn(__fadd_rn(__fmul_rn(x, x), __fmul_rn(y, y)), __fmul_rn(z, z));
                float dot = __fmul_rn(cx, x);
                dot = __fmaf_rn(cy, y, dot);
                dot = __fmaf_rn(cz, z, dot);
                float d2  = __fadd_rn(__fsub_rn(cn, __fmul_rn(2.0f, dot)), xn);
                int p = tid * K2_PPT + c * 4 + j;
                keys[c * 4 + j] =
                    ((unsigned long long)fxform(__float_as_uint(d2)) << 32) | (unsigned)p;
            }
        }

        bitonic_sort<K2_PPT>(keys);

        // per-wave top-32 extraction (ascending into wtop[wid])
        {
            unsigned long long cand = keys[0];
            unsigned w = 0;
            for (int r = 0; r < GSIZE; ++r) {
                unsigned ch = (unsigned)(cand >> 32);
                unsigned whd = (unsigned)rdlane63_i((int)wave_umin32(ch));
                unsigned long long bal = __ballot(ch == whd);
                unsigned wl;
                if (__popcll(bal) == 1) {
                    int L = (int)(__ffsll((long long)bal) - 1);
                    wl = (unsigned)__builtin_amdgcn_readlane((int)(unsigned)cand, L);
                } else {
                    unsigned cl = (ch == whd) ? (unsigned)cand : 0xFFFFFFFFu;
                    wl = (unsigned)rdlane63_i((int)wave_umin32(cl));
                }
                unsigned long long wkey = ((unsigned long long)whd << 32) | wl;
                if (lane == 0) S.k.wtop[wid][r] = wkey;
                if (cand == wkey) {   // exactly one lane (keys unique)
                    ++w;
                    unsigned long long nc;
                    if (w < 4) {
                        nc = (w == 1) ? keys[1] : (w == 2) ? keys[2] : keys[3];
                    } else if (w < K2_PPT) {
                        nc = keys[4];
#pragma unroll
                        for (int j = 5; j < K2_PPT; ++j) nc = (w == (unsigned)j) ? keys[j] : nc;
                    } else {
                        nc = ~0ull;
                    }
                    cand = nc;
                }
            }
        }
        __syncthreads();

        // parallel rank-merge: 256 threads, one candidate each
        if (tid < K2_WAVES * GSIZE) {
            const int w8 = tid >> 5, i = tid & 31;
            unsigned long long e = S.k.wtop[w8][i];
            int rank = 0;
#pragma unroll
            for (int l = 0; l < K2_WAVES; ++l) {
                const unsigned long long* arr = S.k.wtop[l];
                int lo = 0;
                if (arr[15]     < e) lo = 16;
                if (arr[lo + 7] < e) lo += 8;
                if (arr[lo + 3] < e) lo += 4;
                if (arr[lo + 1] < e) lo += 2;
                if (arr[lo]     < e) lo += 1;
                rank += lo;
            }
            if (rank < GSIZE) S.k.nlist[rank] = (unsigned)e;
        }
        __syncthreads();

        // ---- outputs ----
        if (tid < GSIZE) {
            unsigned p = S.k.nlist[tid];
            float x  = base[p * 6 + 0];
            float y  = base[p * 6 + 1];
            float z  = base[p * 6 + 2];
            float a0 = base[p * 6 + 3];
            float a1 = base[p * 6 + 4];
            float a2 = base[p * 6 + 5];
            size_t o = ((size_t)(b * NGROUP + g) * GSIZE + tid) * 3;
            out[o + 0] = __fsub_rn(x, cx);
            out[o + 1] = __fsub_rn(y, cy);
            out[o + 2] = __fsub_rn(z, cz);
            out[OFF1 + o + 0] = a0;
            out[OFF1 + o + 1] = a1;
            out[OFF1 + o + 2] = a2;
        } else if (tid == GSIZE) {
            size_t o = (size_t)(b * NGROUP + g) * 3;
            out[OFF2 + o + 0] = cx;
            out[OFF2 + o + 1] = cy;
            out[OFF2 + o + 2] = cz;
            out[OFF3 + o + 0] = base[qq * 6 + 3];
            out[OFF3 + o + 1] = base[qq * 6 + 4];
            out[OFF3 + o + 2] = base[qq * 6 + 5];
        }
        // no trailing barrier: next iteration's top __syncthreads orders S.k reuse
    }
}

extern "C" void kernel_launch(void* const* d_in, const int* in_sizes, int n_in,
                              void* d_out, int out_size, void* d_ws, size_t ws_size,
                              hipStream_t stream) {
    const float* xyz = (const float*)d_in[0];
    float* out = (float*)d_out;
    int* fps_idx = (int*)d_ws;   // 16 KB; 0xAA poison < 0 = "not ready" sentinel

    fused_kernel<<<TOT_BLOCKS, THREADS, 0, stream>>>(xyz, out, fps_idx);
}

// Round 11
// 515.793 us; speedup vs baseline: 1.1458x; 1.1458x over previous
//
#include <hip/hip_runtime.h>
#include <stdint.h>

#define N_PTS 8192
#define N_B 8
#define NGROUP 512
#define GSIZE 32
#define BIGF 1e10f

#define THREADS 512
#define TOT_BLOCKS 256
#define FPS_BLOCKS 8
#define KNN_BLOCKS (TOT_BLOCKS - FPS_BLOCKS)   // 248

#define K1_PPT 16            // fps points per thread
#define K1_WAVES 8

#define K2_PPT 16
#define K2_WAVES 8

// partial record: 48B stride (12 words) -> record w words {12w,12w+1} mod 32 are
// pairwise disjoint banks; lanes sharing a record broadcast. Conflict-free.
#define PART_STRIDE 12

#define FMAX3(a, b, c) fmaxf(fmaxf((a), (b)), (c))

typedef float v2f __attribute__((ext_vector_type(2)));

// ---------------- DPP reductions ------------------------------------------------------
#define DPP_STEP_UMIN(ctrl, rmask)                                                 \
    { unsigned t = (unsigned)__builtin_amdgcn_update_dpp(                          \
            (int)v, (int)v, ctrl, rmask, 0xF, false);                              \
      v = (t < v) ? t : v; }

__device__ __forceinline__ unsigned wave_umin32(unsigned v) {
    DPP_STEP_UMIN(0x111, 0xF);
    DPP_STEP_UMIN(0x112, 0xF);
    DPP_STEP_UMIN(0x114, 0xF);
    DPP_STEP_UMIN(0x118, 0xF);
    DPP_STEP_UMIN(0x142, 0xA);
    DPP_STEP_UMIN(0x143, 0xC);
    return v;   // lane 63 valid
}

#define DPP_STEP_FMAX(ctrl, rmask)                                                 \
    v = fmaxf(v, __int_as_float(__builtin_amdgcn_update_dpp(                       \
            __float_as_int(v), __float_as_int(v), ctrl, rmask, 0xF, false)))

__device__ __forceinline__ float wave_fmax(float v) {
    DPP_STEP_FMAX(0x111, 0xF);
    DPP_STEP_FMAX(0x112, 0xF);
    DPP_STEP_FMAX(0x114, 0xF);
    DPP_STEP_FMAX(0x118, 0xF);
    DPP_STEP_FMAX(0x142, 0xA);
    DPP_STEP_FMAX(0x143, 0xC);
    return v;   // lane 63 valid
}

// 3-step f32 DPP max over 8-lane groups (records replicate every 8 lanes)
__device__ __forceinline__ float group8_fmax(float v) {
    DPP_STEP_FMAX(0x111, 0xF);
    DPP_STEP_FMAX(0x112, 0xF);
    DPP_STEP_FMAX(0x114, 0xF);
    return v;   // lane 63 valid (max of its 8-group == max of all 8 records)
}

__device__ __forceinline__ int rdlane63_i(int v) {
    return __builtin_amdgcn_readlane(v, 63);
}

__device__ __forceinline__ unsigned fxform(unsigned u) {
    return u ^ (unsigned)(((int)u >> 31) | 0x80000000);
}

// bitonic sort (ascending) of an N-element register array of u64
template<int N>
__device__ __forceinline__ void bitonic_sort(unsigned long long* a) {
#pragma unroll
    for (int k = 2; k <= N; k <<= 1) {
#pragma unroll
        for (int j = k >> 1; j > 0; j >>= 1) {
#pragma unroll
            for (int i = 0; i < N; ++i) {
                int ixj = i ^ j;
                if (ixj > i) {
                    bool up = ((i & k) == 0);
                    unsigned long long x = a[i], y = a[ixj];
                    bool sw = up ? (x > y) : (x < y);
                    if (sw) { a[i] = y; a[ixj] = x; }
                }
            }
        }
    }
}

// LDS overlay: fps needs swizzled lx/ly/lz + partial records; knn needs wtop+nlist+qshare.
union SharedLDS {
    struct {
        float lx[N_PTS]; float ly[N_PTS]; float lz[N_PTS];   // 96 KB, swizzled
        // record w at [w*12]: word 0 = dist bits, word 1 = global idx
        unsigned part[2][K1_WAVES * PART_STRIDE];            // dbuf, 768 B
    } f;
    struct {
        unsigned long long wtop[K2_WAVES][GSIZE];            // 2 KB
        unsigned nlist[GSIZE];
        int qshare;
    } k;
};

// ---------------- fused kernel --------------------------------------------------------
// Blocks 0..7: FPS (R7 structure — best measured across 10 experiment rounds: R2
// pre-barrier chain [lane-0 write + readlane; dynamic-lane writes cost 40-90us,
// measured 4x] + overlapped post-barrier coord window. Refuted alternatives:
// multi-batch (R3), coord-in-record folds (R4/R5/R6), barrier-free spin (R8),
// packed min/max rewrite (R9), lane==L partial write (R10)).
// fps_idx written once per group with a RELAXED agent atomic store — the datum is
// its own ready-flag (poison 0xAA < 0, indices >= 0).
// Blocks 8..255: kNN workers; tid0 RELAXED-atomic-spins on fps_idx[b,g] >= 0, LDS-
// broadcasts it, __syncthreads() orders the block.
extern "C" __global__ __launch_bounds__(THREADS, 1) void fused_kernel(
    const float* __restrict__ xyz, float* __restrict__ out,
    int* __restrict__ fps_idx)
{
    __shared__ SharedLDS S;
    const int bid = blockIdx.x;
    const int tid = threadIdx.x;
    const int lane = tid & 63;
    const int wid  = tid >> 6;

    if (bid < FPS_BLOCKS) {
        // =========================== FPS (batch = bid) ===============================
        const int b = bid;
        const float* base = xyz + (size_t)b * N_PTS * 6;
        const float4* b4 = (const float4*)base;

        v2f px[8], py[8], pz[8];
        float dd[K1_PPT];

        const int tb = tid * 24;
#pragma unroll
        for (int c = 0; c < 4; ++c) {
            float4 f0 = b4[tb + c * 6 + 0];
            float4 f1 = b4[tb + c * 6 + 1];
            float4 f2 = b4[tb + c * 6 + 2];
            float4 f3 = b4[tb + c * 6 + 3];
            float4 f4 = b4[tb + c * 6 + 4];
            float4 f5 = b4[tb + c * 6 + 5];
            px[c * 2 + 0] = (v2f){f0.x, f1.z};
            py[c * 2 + 0] = (v2f){f0.y, f1.w};
            pz[c * 2 + 0] = (v2f){f0.z, f2.x};
            px[c * 2 + 1] = (v2f){f3.x, f4.z};
            py[c * 2 + 1] = (v2f){f3.y, f4.w};
            pz[c * 2 + 1] = (v2f){f3.z, f5.x};
        }
        // swizzled staging: point p = tid*16+i at A(p) = (i<<9)+tid (conflict-free)
#pragma unroll
        for (int i = 0; i < K1_PPT; ++i) {
            int a = (i << 9) + tid;
            S.f.lx[a] = px[i >> 1][i & 1];
            S.f.ly[a] = py[i >> 1][i & 1];
            S.f.lz[a] = pz[i >> 1][i & 1];
            dd[i] = BIGF;
        }
        __syncthreads();

        unsigned cur = 0;
        float cx = S.f.lx[0], cy = S.f.ly[0], cz = S.f.lz[0];   // point 0: A(0)=0

        for (int it = 0; it < NGROUP; ++it) {
            if (tid == 0) {
                // single relaxed store: fire-and-forget; datum doubles as flag.
                // NOTE: intentionally never vmcnt-drained inside the loop.
                __hip_atomic_store(&fps_idx[b * NGROUP + it], (int)cur,
                                   __ATOMIC_RELAXED, __HIP_MEMORY_SCOPE_AGENT);
            }
            if (it == NGROUP - 1) break;

            // packed min-update: per pair v_pk_sub x3, v_pk_mul x3, v_pk_add x2.
            // contract(off) forbids mul+add fusion -> exact (dx^2+dy^2)+dz^2 order,
            // bitwise identical per half to the scalar reference path.
            {
#pragma clang fp contract(off)
                v2f c2x = {cx, cx};
                v2f c2y = {cy, cy};
                v2f c2z = {cz, cz};
#pragma unroll
                for (int q = 0; q < 8; ++q) {
                    v2f dx = px[q] - c2x;
                    v2f dy = py[q] - c2y;
                    v2f dz = pz[q] - c2z;
                    v2f s  = (dx * dx + dy * dy) + dz * dz;
                    dd[2 * q + 0] = fminf(dd[2 * q + 0], s[0]);
                    dd[2 * q + 1] = fminf(dd[2 * q + 1], s[1]);
                }
            }

            // post-loop argmax: v_max3 tree (8 ops) + downward equality scan
            // (keeps SMALLEST matching i -> identical tie semantics to running '>').
            float t0 = FMAX3(dd[0],  dd[1],  dd[2]);
            float t1 = FMAX3(dd[3],  dd[4],  dd[5]);
            float t2 = FMAX3(dd[6],  dd[7],  dd[8]);
            float t3 = FMAX3(dd[9],  dd[10], dd[11]);
            float t4 = FMAX3(dd[12], dd[13], dd[14]);
            float bestd = fmaxf(FMAX3(t0, t1, t2), FMAX3(t3, t4, dd[15]));
            unsigned besti = 0;
#pragma unroll
            for (int i = K1_PPT - 1; i >= 0; --i)
                besti = (dd[i] == bestd) ? (unsigned)i : besti;

            unsigned bestp = (unsigned)tid * K1_PPT + besti;

            // wave argmax: f32 DPP max, then first tied lane (= smallest global index)
            // — lane-0 write + readlane (dynamic-lane writes measured 40-90us slower).
            float wm = __int_as_float(rdlane63_i(__float_as_int(wave_fmax(bestd))));
            unsigned long long bal = __ballot(bestd == wm);
            int L = (int)(__ffsll((long long)bal) - 1);
            unsigned widx = (unsigned)__builtin_amdgcn_readlane((int)bestp, L);

            // 2-word partial {dist, idx}: one pair per wave.
            if (lane == 0) {
                unsigned* rec = &S.f.part[it & 1][wid * PART_STRIDE];
                rec[0] = __float_as_uint(wm);
                rec[1] = widx;
            }

            // barrier WITHOUT the implicit vmcnt(0) drain of __syncthreads():
            // only the LDS write must be visible (lgkmcnt); the relaxed fps_idx
            // publish store stays in flight across the barrier. (R8 measured the
            // barrier-free spin alternative at +120us — s_barrier is the cheap path.)
            asm volatile("s_waitcnt lgkmcnt(0)" ::: "memory");
            __builtin_amdgcn_s_barrier();
            __builtin_amdgcn_sched_barrier(0);   // pin the ds_reads below after barrier

            // Window 1: read record (lane&7) = {dist, idx}.
            const unsigned* rr = &S.f.part[it & 1][(lane & 7) * PART_STRIDE];
            float    rv = __uint_as_float(rr[0]);
            unsigned ri = rr[1];

            // Speculative coord read for candidate (lane&7), issued IMMEDIATELY —
            // overlaps the DPP reduce below. 8 distinct addresses × 8-lane broadcast
            // groups. Unconditionally consumed by readlane -> cannot be sunk (R4 bug).
            int wa = (int)(((ri & 15u) << 9) + (ri >> 4));
            float rx = S.f.lx[wa];
            float ry = S.f.ly[wa];
            float rz = S.f.lz[wa];
            __builtin_amdgcn_sched_barrier(0);   // coord reads issue before the chain

            // Slim reduce: 3-step f32 DPP max over dist + ballot. First tied lane =
            // smallest record id = smallest wave id = smallest global index (wave
            // index ranges disjoint & ascending; each record carries its wave's
            // smallest tied index) — identical tie semantics to the u64-key path.
            float wm2 = __int_as_float(rdlane63_i(__float_as_int(group8_fmax(rv))));
            unsigned long long b2 = __ballot(rv == wm2);
            int W = (int)(__ffsll((long long)b2) - 1);   // in [0,8)
            cur = (unsigned)__builtin_amdgcn_readlane((int)ri, W);
            // Coord data arrived during the DPP chain; lane W holds winner's coords.
            cx = __int_as_float(__builtin_amdgcn_readlane(__float_as_int(rx), W));
            cy = __int_as_float(__builtin_amdgcn_readlane(__float_as_int(ry), W));
            cz = __int_as_float(__builtin_amdgcn_readlane(__float_as_int(rz), W));
        }
        return;
    }

    // ============================= kNN worker blocks =================================
    const int OFF1 = N_B * NGROUP * GSIZE * 3;   // neigh_attr
    const int OFF2 = 2 * OFF1;                   // center
    const int OFF3 = OFF2 + N_B * NGROUP * 3;    // center_attribute

    for (int idx = bid - FPS_BLOCKS; idx < N_B * NGROUP; idx += KNN_BLOCKS) {
        const int g = idx >> 3;
        const int b = idx & 7;
        const float* base = xyz + (size_t)b * N_PTS * 6;

        if (tid == 0) {
            // relaxed atomic spin on the datum itself (L2 read, caches stay warm)
            int qv;
            while ((qv = __hip_atomic_load(&fps_idx[b * NGROUP + g], __ATOMIC_RELAXED,
                                           __HIP_MEMORY_SCOPE_AGENT)) < 0)
                __builtin_amdgcn_s_sleep(32);
            S.k.qshare = qv;
        }
        __syncthreads();   // orders qshare + all S.k reuse from previous group

        const int qq = __builtin_amdgcn_readfirstlane(S.k.qshare);
        const float cx = base[qq * 6 + 0];
        const float cy = base[qq * 6 + 1];
        const float cz = base[qq * 6 + 2];
        // ||c||^2: separate square, left-assoc add, NO FMA
        const float cn = __fadd_rn(__fadd_rn(__fmul_rn(cx, cx), __fmul_rn(cy, cy)),
                                   __fmul_rn(cz, cz));

        const float4* b4 = (const float4*)base;
        const int tb = tid * 24;

        unsigned long long keys[K2_PPT];

#pragma unroll
        for (int c = 0; c < 4; ++c) {
            float4 f0 = b4[tb + c * 6 + 0];
            float4 f1 = b4[tb + c * 6 + 1];
            float4 f2 = b4[tb + c * 6 + 2];
            float4 f3 = b4[tb + c * 6 + 3];
            float4 f4 = b4[tb + c * 6 + 4];
            float4 f5 = b4[tb + c * 6 + 5];
            float X[4] = {f0.x, f1.z, f3.x, f4.z};
            float Y[4] = {f0.y, f1.w, f3.y, f4.w};
            float Z[4] = {f0.z, f2.x, f3.z, f5.x};
#pragma unroll
            for (int j = 0; j < 4; ++j) {
                float x = X[j], y = Y[j], z = Z[j];
                float xn  = __fadd_rn(__fadd_rn(__fmul_rn(x, x), __fmul_rn(y, y)), __fmul_rn(z, z));
                float dot = __fmul_rn(cx, x);
                dot = __fmaf_rn(cy, y, dot);
                dot = __fmaf_rn(cz, z, dot);
                float d2  = __fadd_rn(__fsub_rn(cn, __fmul_rn(2.0f, dot)), xn);
                int p = tid * K2_PPT + c * 4 + j;
                keys[c * 4 + j] =
                    ((unsigned long long)fxform(__float_as_uint(d2)) << 32) | (unsigned)p;
            }
        }

        bitonic_sort<K2_PPT>(keys);

        // per-wave top-32 extraction (ascending into wtop[wid])
        {
            unsigned long long cand = keys[0];
            unsigned w = 0;
            for (int r = 0; r < GSIZE; ++r) {
                unsigned ch = (unsigned)(cand >> 32);
                unsigned whd = (unsigned)rdlane63_i((int)wave_umin32(ch));
                unsigned long long bal = __ballot(ch == whd);
                unsigned wl;
                if (__popcll(bal) == 1) {
                    int L = (int)(__ffsll((long long)bal) - 1);
                    wl = (unsigned)__builtin_amdgcn_readlane((int)(unsigned)cand, L);
                } else {
                    unsigned cl = (ch == whd) ? (unsigned)cand : 0xFFFFFFFFu;
                    wl = (unsigned)rdlane63_i((int)wave_umin32(cl));
                }
                unsigned long long wkey = ((unsigned long long)whd << 32) | wl;
                if (lane == 0) S.k.wtop[wid][r] = wkey;
                if (cand == wkey) {   // exactly one lane (keys unique)
                    ++w;
                    unsigned long long nc;
                    if (w < 4) {
                        nc = (w == 1) ? keys[1] : (w == 2) ? keys[2] : keys[3];
                    } else if (w < K2_PPT) {
                        nc = keys[4];
#pragma unroll
                        for (int j = 5; j < K2_PPT; ++j) nc = (w == (unsigned)j) ? keys[j] : nc;
                    } else {
                        nc = ~0ull;
                    }
                    cand = nc;
                }
            }
        }
        __syncthreads();

        // parallel rank-merge: 256 threads, one candidate each
        if (tid < K2_WAVES * GSIZE) {
            const int w8 = tid >> 5, i = tid & 31;
            unsigned long long e = S.k.wtop[w8][i];
            int rank = 0;
#pragma unroll
            for (int l = 0; l < K2_WAVES; ++l) {
                const unsigned long long* arr = S.k.wtop[l];
                int lo = 0;
                if (arr[15]     < e) lo = 16;
                if (arr[lo + 7] < e) lo += 8;
                if (arr[lo + 3] < e) lo += 4;
                if (arr[lo + 1] < e) lo += 2;
                if (arr[lo]     < e) lo += 1;
                rank += lo;
            }
            if (rank < GSIZE) S.k.nlist[rank] = (unsigned)e;
        }
        __syncthreads();

        // ---- outputs ----
        if (tid < GSIZE) {
            unsigned p = S.k.nlist[tid];
            float x  = base[p * 6 + 0];
            float y  = base[p * 6 + 1];
            float z  = base[p * 6 + 2];
            float a0 = base[p * 6 + 3];
            float a1 = base[p * 6 + 4];
            float a2 = base[p * 6 + 5];
            size_t o = ((size_t)(b * NGROUP + g) * GSIZE + tid) * 3;
            out[o + 0] = __fsub_rn(x, cx);
            out[o + 1] = __fsub_rn(y, cy);
            out[o + 2] = __fsub_rn(z, cz);
            out[OFF1 + o + 0] = a0;
            out[OFF1 + o + 1] = a1;
            out[OFF1 + o + 2] = a2;
        } else if (tid == GSIZE) {
            size_t o = (size_t)(b * NGROUP + g) * 3;
            out[OFF2 + o + 0] = cx;
            out[OFF2 + o + 1] = cy;
            out[OFF2 + o + 2] = cz;
            out[OFF3 + o + 0] = base[qq * 6 + 3];
            out[OFF3 + o + 1] = base[qq * 6 + 4];
            out[OFF3 + o + 2] = base[qq * 6 + 5];
        }
        // no trailing barrier: next iteration's top __syncthreads orders S.k reuse
    }
}

extern "C" void kernel_launch(void* const* d_in, const int* in_sizes, int n_in,
                              void* d_out, int out_size, void* d_ws, size_t ws_size,
                              hipStream_t stream) {
    const float* xyz = (const float*)d_in[0];
    float* out = (float*)d_out;
    int* fps_idx = (int*)d_ws;   // 16 KB; 0xAA poison < 0 = "not ready" sentinel

    fused_kernel<<<TOT_BLOCKS, THREADS, 0, stream>>>(xyz, out, fps_idx);
}